// Round 9
// baseline (369.327 us; speedup 1.0000x reference)
//
#include <hip/hip_runtime.h>

#define NBINS 15

typedef float f32x4 __attribute__((ext_vector_type(4)));
typedef int   i32x4 __attribute__((ext_vector_type(4)));

// Workspace layout (u64 slots): [0..14] per-bin signed sum of wv*(c-corr) in
// 2^-16 fixed point (wrapped two's-complement), [15] total mask sum,
// [16] block-done counter (u32 in low word).
// ECE = sum_b |S_b| / 2^16 / total.

// Process one float4/int4 chunk into acc[]/tot (branchless 15-way select).
#define PROC(cv, pv, tv, mv)                                              \
    {                                                                     \
        _Pragma("unroll")                                                 \
        for (int k = 0; k < 4; ++k) {                                     \
            float c = (cv)[k];                                            \
            int   m = (mv)[k];                                            \
            tot += (unsigned int)m;                                       \
            bool valid = (m != 0) & (c > 0.0f) & (c <= 1.0f);             \
            int bin = (int)ceilf(c * 15.0f) - 1;                          \
            bin = min(max(bin, 0), NBINS - 1);                            \
            bin = valid ? bin : -1;                                       \
            float corr = ((pv)[k] == (tv)[k]) ? 1.0f : 0.0f;              \
            int d = (int)rintf((c - corr) * 65536.0f);                    \
            _Pragma("unroll")                                             \
            for (int b = 0; b < NBINS; ++b)                               \
                acc[b] += (bin == b) ? d : 0;                             \
        }                                                                 \
    }

#define LOADSTAGE(cv, pv, tv, mv, idx)                                    \
    {                                                                     \
        const int _i = (idx);                                             \
        cv = __builtin_nontemporal_load(c4p + _i);                        \
        pv = __builtin_nontemporal_load(p4p + _i);                        \
        tv = __builtin_nontemporal_load(t4p + _i);                        \
        mv = __builtin_nontemporal_load(m4p + _i);                        \
    }

__global__ __launch_bounds__(256, 6) void ece_fused(
    const float* __restrict__ conf,
    const int*   __restrict__ pred,
    const int*   __restrict__ targ,
    const int*   __restrict__ mask,
    unsigned long long* __restrict__ ws,
    float* __restrict__ out,
    int nvec, long long n, int nblocks)
{
    __shared__ unsigned int hsum[16];
    __shared__ unsigned long long stot;
    __shared__ int islast;

    const int tid  = threadIdx.x;
    const int lane = tid & 63;

    if (tid < 16) hsum[tid] = 0u;
    if (tid == 0) { stot = 0ULL; islast = 0; }
    __syncthreads();

    const int gid    = blockIdx.x * blockDim.x + tid;
    const int stride = gridDim.x * blockDim.x;

    const f32x4* __restrict__ c4p = (const f32x4*)conf;
    const i32x4* __restrict__ p4p = (const i32x4*)pred;
    const i32x4* __restrict__ t4p = (const i32x4*)targ;
    const i32x4* __restrict__ m4p = (const i32x4*)mask;

    int acc[NBINS];
#pragma unroll
    for (int b = 0; b < NBINS; ++b) acc[b] = 0;

    unsigned int tot = 0;

    // Scalar tail (n % 4 leftovers) handled by block 0's first lanes.
    if (blockIdx.x == 0) {
        long long base = (long long)nvec * 4;
        if (tid < (int)(n - base)) {
            long long idx = base + tid;
            float c = conf[idx];
            int   m = mask[idx];
            tot += (unsigned int)m;
            bool valid = (m != 0) & (c > 0.0f) & (c <= 1.0f);
            int bin = (int)ceilf(c * 15.0f) - 1;
            bin = min(max(bin, 0), NBINS - 1);
            bin = valid ? bin : -1;
            float corr = (pred[idx] == targ[idx]) ? 1.0f : 0.0f;
            int d = (int)rintf((c - corr) * 65536.0f);
#pragma unroll
            for (int b = 0; b < NBINS; ++b)
                acc[b] += (bin == b) ? d : 0;
        }
    }

    // Three-stage software pipeline: 12 nt loads (12 KB/wave) continuously
    // in flight. Tests whether per-wave in-flight depth (8KB in R5/R8) was
    // the binding concurrency limit.
    int k = gid;
    if (k + 2 * stride < nvec) {
        f32x4 c0, c1, c2; i32x4 p0, p1, p2, t0, t1, t2, m0, m1, m2;
        LOADSTAGE(c0, p0, t0, m0, k);
        LOADSTAGE(c1, p1, t1, m1, k + stride);
        LOADSTAGE(c2, p2, t2, m2, k + 2 * stride);

        for (; k + 5 * stride < nvec; k += 3 * stride) {
            PROC(c0, p0, t0, m0);
            LOADSTAGE(c0, p0, t0, m0, k + 3 * stride);
            PROC(c1, p1, t1, m1);
            LOADSTAGE(c1, p1, t1, m1, k + 4 * stride);
            PROC(c2, p2, t2, m2);
            LOADSTAGE(c2, p2, t2, m2, k + 5 * stride);
        }
        PROC(c0, p0, t0, m0);
        PROC(c1, p1, t1, m1);
        PROC(c2, p2, t2, m2);
        k += 3 * stride;
    }
    // Leftover chunks (0-2 per thread).
    for (; k < nvec; k += stride) {
        f32x4 cz; i32x4 pz, tz, mz;
        LOADSTAGE(cz, pz, tz, mz, k);
        PROC(cz, pz, tz, mz);
    }

    // Once-per-block merge.
#pragma unroll
    for (int b = 0; b < NBINS; ++b) {
        int v = acc[b];
#pragma unroll
        for (int off = 32; off; off >>= 1) v += __shfl_down(v, off, 64);
        acc[b] = v;
    }
    unsigned int v = tot;
#pragma unroll
    for (int off = 32; off; off >>= 1) v += __shfl_down(v, off, 64);

    if (lane == 0) {
#pragma unroll
        for (int b = 0; b < NBINS; ++b)
            if (acc[b] != 0) atomicAdd(&hsum[b], (unsigned int)acc[b]);
        atomicAdd(&stot, (unsigned long long)v);
    }
    __syncthreads();

    if (tid < NBINS) {
        int s = (int)hsum[tid];   // block |sum| <= 2^30, fits i32
        if (s != 0)
            atomicAdd(&ws[tid], (unsigned long long)(long long)s);
    }
    if (tid == NBINS) {
        atomicAdd(&ws[NBINS], stot);
    }
    // Make this thread's ws atomics globally visible before the ticket.
    __threadfence();
    __syncthreads();

    if (tid == 0) {
        unsigned int* done = (unsigned int*)&ws[16];
        unsigned int ticket = atomicAdd(done, 1u);
        islast = (ticket == (unsigned int)(nblocks - 1)) ? 1 : 0;
    }
    __syncthreads();

    // Last block finalizes (device-scope atomic reads -> coherent).
    if (islast && tid < 64) {
        double dv = 0.0;
        unsigned long long totv = 0ULL;
        if (tid < NBINS) {
            long long s = (long long)atomicAdd(&ws[tid], 0ULL);
            dv = fabs((double)s);
        }
        if (tid == NBINS) totv = atomicAdd(&ws[NBINS], 0ULL);
#pragma unroll
        for (int off = 32; off; off >>= 1) dv += __shfl_down(dv, off, 64);
        totv = __shfl(totv, NBINS, 64);
        if (tid == 0) {
            double total = (double)totv;
            if (total < 1.0) total = 1.0;
            out[0] = (float)(dv * (1.0 / 65536.0) / total);
        }
    }
}

extern "C" void kernel_launch(void* const* d_in, const int* in_sizes, int n_in,
                              void* d_out, int out_size, void* d_ws, size_t ws_size,
                              hipStream_t stream)
{
    const float* conf = (const float*)d_in[0];
    const int*   pred = (const int*)d_in[1];
    const int*   targ = (const int*)d_in[2];
    const int*   mask = (const int*)d_in[3];
    long long n    = in_sizes[0];
    int       nvec = (int)(n / 4);

    unsigned long long* ws = (unsigned long long*)d_ws;

    // Zero the 17 u64 accumulator/counter slots (deterministic; capture-safe).
    hipMemsetAsync(d_ws, 0, 17 * sizeof(unsigned long long), stream);

    // 1536 blocks x 256 threads = 6 blocks/CU (best measured: 6 < 7 < 8).
    // (256,6) caps VGPR at 85; 3-stage pipeline needs ~77 -> no spill
    // (guard: WRITE_SIZE must stay ~bytes-of-result, not MB).
    const int nblocks = 1536;
    ece_fused<<<nblocks, 256, 0, stream>>>(conf, pred, targ, mask, ws,
                                           (float*)d_out, nvec, n, nblocks);
}

// Round 10
// 347.548 us; speedup vs baseline: 1.0627x; 1.0627x over previous
//
#include <hip/hip_runtime.h>

#define NBINS 15

typedef float f32x4 __attribute__((ext_vector_type(4)));
typedef int   i32x4 __attribute__((ext_vector_type(4)));

// Workspace layout (u64 slots): [0..14] per-bin signed sum of wv*(c-corr) in
// 2^-16 fixed point (wrapped two's-complement), [15] total mask sum,
// [16] block-done counter (u32 in low word).
// ECE = sum_b |S_b| / 2^16 / total.

// Process one float4/int4 chunk into acc[]/tot (branchless 15-way select).
#define PROC(cv, pv, tv, mv)                                              \
    {                                                                     \
        _Pragma("unroll")                                                 \
        for (int k = 0; k < 4; ++k) {                                     \
            float c = (cv)[k];                                            \
            int   m = (mv)[k];                                            \
            tot += (unsigned int)m;                                       \
            bool valid = (m != 0) & (c > 0.0f) & (c <= 1.0f);             \
            int bin = (int)ceilf(c * 15.0f) - 1;                          \
            bin = min(max(bin, 0), NBINS - 1);                            \
            bin = valid ? bin : -1;                                       \
            float corr = ((pv)[k] == (tv)[k]) ? 1.0f : 0.0f;              \
            int d = (int)rintf((c - corr) * 65536.0f);                    \
            _Pragma("unroll")                                             \
            for (int b = 0; b < NBINS; ++b)                               \
                acc[b] += (bin == b) ? d : 0;                             \
        }                                                                 \
    }

__global__ __launch_bounds__(256, 6) void ece_fused(
    const float* __restrict__ conf,
    const int*   __restrict__ pred,
    const int*   __restrict__ targ,
    const int*   __restrict__ mask,
    unsigned long long* __restrict__ ws,
    float* __restrict__ out,
    int nvec, long long n, int nblocks)
{
    __shared__ unsigned int hsum[16];
    __shared__ unsigned long long stot;
    __shared__ int islast;

    const int tid  = threadIdx.x;
    const int lane = tid & 63;

    if (tid < 16) hsum[tid] = 0u;
    if (tid == 0) { stot = 0ULL; islast = 0; }
    __syncthreads();

    const int gid    = blockIdx.x * blockDim.x + tid;
    const int stride = gridDim.x * blockDim.x;

    const f32x4* __restrict__ c4p = (const f32x4*)conf;
    const i32x4* __restrict__ p4p = (const i32x4*)pred;
    const i32x4* __restrict__ t4p = (const i32x4*)targ;
    const i32x4* __restrict__ m4p = (const i32x4*)mask;

    int acc[NBINS];
#pragma unroll
    for (int b = 0; b < NBINS; ++b) acc[b] = 0;

    unsigned int tot = 0;

    // Scalar tail (n % 4 leftovers) handled by block 0's first lanes.
    // (No-op for this problem's shape: n % 4 == 0.)
    if (blockIdx.x == 0) {
        long long base = (long long)nvec * 4;
        if (tid < (int)(n - base)) {
            long long idx = base + tid;
            float c = conf[idx];
            int   m = mask[idx];
            tot += (unsigned int)m;
            bool valid = (m != 0) & (c > 0.0f) & (c <= 1.0f);
            int bin = (int)ceilf(c * 15.0f) - 1;
            bin = min(max(bin, 0), NBINS - 1);
            bin = valid ? bin : -1;
            float corr = (pred[idx] == targ[idx]) ? 1.0f : 0.0f;
            int d = (int)rintf((c - corr) * 65536.0f);
#pragma unroll
            for (int b = 0; b < NBINS; ++b)
                acc[b] += (bin == b) ? d : 0;
        }
    }

    // Two-stage software pipeline -- EXACTLY R8's structure (107.5us, VGPR 40,
    // zero spill). R9's 3-stage variant spilled (WRITE_SIZE 240B -> 185MB).
    int k = gid;
    if (k + stride < nvec) {
        f32x4 c0 = __builtin_nontemporal_load(c4p + k);
        i32x4 p0 = __builtin_nontemporal_load(p4p + k);
        i32x4 t0 = __builtin_nontemporal_load(t4p + k);
        i32x4 m0 = __builtin_nontemporal_load(m4p + k);
        f32x4 c1 = __builtin_nontemporal_load(c4p + (k + stride));
        i32x4 p1 = __builtin_nontemporal_load(p4p + (k + stride));
        i32x4 t1 = __builtin_nontemporal_load(t4p + (k + stride));
        i32x4 m1 = __builtin_nontemporal_load(m4p + (k + stride));

        for (; k + 3 * stride < nvec; k += 2 * stride) {
            PROC(c0, p0, t0, m0);
            {
                const int n0 = k + 2 * stride;
                c0 = __builtin_nontemporal_load(c4p + n0);
                p0 = __builtin_nontemporal_load(p4p + n0);
                t0 = __builtin_nontemporal_load(t4p + n0);
                m0 = __builtin_nontemporal_load(m4p + n0);
            }
            PROC(c1, p1, t1, m1);
            {
                const int n1 = k + 3 * stride;
                c1 = __builtin_nontemporal_load(c4p + n1);
                p1 = __builtin_nontemporal_load(p4p + n1);
                t1 = __builtin_nontemporal_load(t4p + n1);
                m1 = __builtin_nontemporal_load(m4p + n1);
            }
        }
        // Drain the two live stages (indices k, k+stride).
        PROC(c0, p0, t0, m0);
        PROC(c1, p1, t1, m1);
        k += 2 * stride;
    }
    // Tail: at most one leftover chunk per thread (plus the no-pipeline case).
    for (; k < nvec; k += stride) {
        f32x4 cz = __builtin_nontemporal_load(c4p + k);
        i32x4 pz = __builtin_nontemporal_load(p4p + k);
        i32x4 tz = __builtin_nontemporal_load(t4p + k);
        i32x4 mz = __builtin_nontemporal_load(m4p + k);
        PROC(cz, pz, tz, mz);
    }

    // Once-per-block merge.
#pragma unroll
    for (int b = 0; b < NBINS; ++b) {
        int v = acc[b];
#pragma unroll
        for (int off = 32; off; off >>= 1) v += __shfl_down(v, off, 64);
        acc[b] = v;
    }
    unsigned int v = tot;
#pragma unroll
    for (int off = 32; off; off >>= 1) v += __shfl_down(v, off, 64);

    if (lane == 0) {
#pragma unroll
        for (int b = 0; b < NBINS; ++b)
            if (acc[b] != 0) atomicAdd(&hsum[b], (unsigned int)acc[b]);
        atomicAdd(&stot, (unsigned long long)v);
    }
    __syncthreads();

    if (tid < NBINS) {
        int s = (int)hsum[tid];   // block |sum| <= 2^30, fits i32
        if (s != 0)
            atomicAdd(&ws[tid], (unsigned long long)(long long)s);
    }
    if (tid == NBINS) {
        atomicAdd(&ws[NBINS], stot);
    }
    // Make this block's ws atomics globally visible before taking a ticket.
    __threadfence();
    __syncthreads();

    if (tid == 0) {
        unsigned int* done = (unsigned int*)&ws[16];
        unsigned int ticket = atomicAdd(done, 1u);
        islast = (ticket == (unsigned int)(nblocks - 1)) ? 1 : 0;
    }
    __syncthreads();

    // Last block finalizes (device-scope atomic reads -> coherent).
    if (islast && tid < 64) {
        double dv = 0.0;
        unsigned long long totv = 0ULL;
        if (tid < NBINS) {
            long long s = (long long)atomicAdd(&ws[tid], 0ULL);
            dv = fabs((double)s);
        }
        if (tid == NBINS) totv = atomicAdd(&ws[NBINS], 0ULL);
#pragma unroll
        for (int off = 32; off; off >>= 1) dv += __shfl_down(dv, off, 64);
        totv = __shfl(totv, NBINS, 64);
        if (tid == 0) {
            double total = (double)totv;
            if (total < 1.0) total = 1.0;
            out[0] = (float)(dv * (1.0 / 65536.0) / total);
        }
    }
}

extern "C" void kernel_launch(void* const* d_in, const int* in_sizes, int n_in,
                              void* d_out, int out_size, void* d_ws, size_t ws_size,
                              hipStream_t stream)
{
    const float* conf = (const float*)d_in[0];
    const int*   pred = (const int*)d_in[1];
    const int*   targ = (const int*)d_in[2];
    const int*   mask = (const int*)d_in[3];
    long long n    = in_sizes[0];
    int       nvec = (int)(n / 4);

    unsigned long long* ws = (unsigned long long*)d_ws;

    // Zero the 17 u64 accumulator/counter slots (deterministic; capture-safe).
    hipMemsetAsync(d_ws, 0, 17 * sizeof(unsigned long long), stream);

    // 1536 blocks x 256 threads = 6 blocks/CU (best measured: 6 < 7 < 8).
    const int nblocks = 1536;
    ece_fused<<<nblocks, 256, 0, stream>>>(conf, pred, targ, mask, ws,
                                           (float*)d_out, nvec, n, nblocks);
}

// Round 11
// 119.510 us; speedup vs baseline: 3.0903x; 2.9081x over previous
//
#include <hip/hip_runtime.h>

#define NBINS 15

typedef float f32x4 __attribute__((ext_vector_type(4)));
typedef int   i32x4 __attribute__((ext_vector_type(4)));

// Workspace layout (u64 slots): [0..14] per-bin signed sum of wv*(c-corr) in
// 2^-16 fixed point (wrapped two's-complement), [15] total mask sum,
// [16] block-done counter (u32 in low word).
// ECE = sum_b |S_b| / 2^16 / total.

// Process one float4/int4 chunk into acc[]/tot (branchless 15-way select).
#define PROC(cv, pv, tv, mv)                                              \
    {                                                                     \
        _Pragma("unroll")                                                 \
        for (int k = 0; k < 4; ++k) {                                     \
            float c = (cv)[k];                                            \
            int   m = (mv)[k];                                            \
            tot += (unsigned int)m;                                       \
            bool valid = (m != 0) & (c > 0.0f) & (c <= 1.0f);             \
            int bin = (int)ceilf(c * 15.0f) - 1;                          \
            bin = min(max(bin, 0), NBINS - 1);                            \
            bin = valid ? bin : -1;                                       \
            float corr = ((pv)[k] == (tv)[k]) ? 1.0f : 0.0f;              \
            int d = (int)rintf((c - corr) * 65536.0f);                    \
            _Pragma("unroll")                                             \
            for (int b = 0; b < NBINS; ++b)                               \
                acc[b] += (bin == b) ? d : 0;                             \
        }                                                                 \
    }

__global__ __launch_bounds__(256, 6) void ece_fused(
    const float* __restrict__ conf,
    const int*   __restrict__ pred,
    const int*   __restrict__ targ,
    const int*   __restrict__ mask,
    unsigned long long* __restrict__ ws,
    float* __restrict__ out,
    int nvec, long long n, int nblocks)
{
    __shared__ unsigned int hsum[16];
    __shared__ unsigned long long stot;
    __shared__ int islast;

    const int tid  = threadIdx.x;
    const int lane = tid & 63;

    if (tid < 16) hsum[tid] = 0u;
    if (tid == 0) { stot = 0ULL; islast = 0; }
    __syncthreads();

    const int gid    = blockIdx.x * blockDim.x + tid;
    const int stride = gridDim.x * blockDim.x;

    const f32x4* __restrict__ c4p = (const f32x4*)conf;
    const i32x4* __restrict__ p4p = (const i32x4*)pred;
    const i32x4* __restrict__ t4p = (const i32x4*)targ;
    const i32x4* __restrict__ m4p = (const i32x4*)mask;

    int acc[NBINS];
#pragma unroll
    for (int b = 0; b < NBINS; ++b) acc[b] = 0;

    unsigned int tot = 0;

    // Scalar tail (n % 4 leftovers) handled by block 0's first lanes.
    // (No-op for this problem's shape: n % 4 == 0.)
    if (blockIdx.x == 0) {
        long long base = (long long)nvec * 4;
        if (tid < (int)(n - base)) {
            long long idx = base + tid;
            float c = conf[idx];
            int   m = mask[idx];
            tot += (unsigned int)m;
            bool valid = (m != 0) & (c > 0.0f) & (c <= 1.0f);
            int bin = (int)ceilf(c * 15.0f) - 1;
            bin = min(max(bin, 0), NBINS - 1);
            bin = valid ? bin : -1;
            float corr = (pred[idx] == targ[idx]) ? 1.0f : 0.0f;
            int d = (int)rintf((c - corr) * 65536.0f);
#pragma unroll
            for (int b = 0; b < NBINS; ++b)
                acc[b] += (bin == b) ? d : 0;
        }
    }

    // Two-stage software pipeline -- R8's structure (107.5us, VGPR 40, no
    // spill). R9's 3-stage spilled (WRITE_SIZE 185MB); don't deepen.
    int k = gid;
    if (k + stride < nvec) {
        f32x4 c0 = __builtin_nontemporal_load(c4p + k);
        i32x4 p0 = __builtin_nontemporal_load(p4p + k);
        i32x4 t0 = __builtin_nontemporal_load(t4p + k);
        i32x4 m0 = __builtin_nontemporal_load(m4p + k);
        f32x4 c1 = __builtin_nontemporal_load(c4p + (k + stride));
        i32x4 p1 = __builtin_nontemporal_load(p4p + (k + stride));
        i32x4 t1 = __builtin_nontemporal_load(t4p + (k + stride));
        i32x4 m1 = __builtin_nontemporal_load(m4p + (k + stride));

        for (; k + 3 * stride < nvec; k += 2 * stride) {
            PROC(c0, p0, t0, m0);
            {
                const int n0 = k + 2 * stride;
                c0 = __builtin_nontemporal_load(c4p + n0);
                p0 = __builtin_nontemporal_load(p4p + n0);
                t0 = __builtin_nontemporal_load(t4p + n0);
                m0 = __builtin_nontemporal_load(m4p + n0);
            }
            PROC(c1, p1, t1, m1);
            {
                const int n1 = k + 3 * stride;
                c1 = __builtin_nontemporal_load(c4p + n1);
                p1 = __builtin_nontemporal_load(p4p + n1);
                t1 = __builtin_nontemporal_load(t4p + n1);
                m1 = __builtin_nontemporal_load(m4p + n1);
            }
        }
        // Drain the two live stages (indices k, k+stride).
        PROC(c0, p0, t0, m0);
        PROC(c1, p1, t1, m1);
        k += 2 * stride;
    }
    // Tail: at most one leftover chunk per thread (plus the no-pipeline case).
    for (; k < nvec; k += stride) {
        f32x4 cz = __builtin_nontemporal_load(c4p + k);
        i32x4 pz = __builtin_nontemporal_load(p4p + k);
        i32x4 tz = __builtin_nontemporal_load(t4p + k);
        i32x4 mz = __builtin_nontemporal_load(m4p + k);
        PROC(cz, pz, tz, mz);
    }

    // Once-per-block merge.
#pragma unroll
    for (int b = 0; b < NBINS; ++b) {
        int v = acc[b];
#pragma unroll
        for (int off = 32; off; off >>= 1) v += __shfl_down(v, off, 64);
        acc[b] = v;
    }
    unsigned int v = tot;
#pragma unroll
    for (int off = 32; off; off >>= 1) v += __shfl_down(v, off, 64);

    if (lane == 0) {
#pragma unroll
        for (int b = 0; b < NBINS; ++b)
            if (acc[b] != 0) atomicAdd(&hsum[b], (unsigned int)acc[b]);
        atomicAdd(&stot, (unsigned long long)v);
    }
    __syncthreads();

    if (tid < NBINS) {
        int s = (int)hsum[tid];   // block |sum| <= 2^30, fits i32
        if (s != 0)
            atomicAdd(&ws[tid], (unsigned long long)(long long)s);
    }
    if (tid == NBINS) {
        atomicAdd(&ws[NBINS], stot);
    }
    // Ordering: ALL ws traffic is device-scope atomics (performed at the
    // coherent point), so visibility needs no L2 writeback. We only need
    // this wave's bin-atomics to COMPLETE before the ticket atomic issues:
    // s_waitcnt vmcnt(0), wave-local and ~free.
    // (R9/R10 used __threadfence() here -> buffer_wbl2 L2-writeback per
    // wave x 6144 waves = the 108->354us regression.)
    asm volatile("s_waitcnt vmcnt(0)" ::: "memory");
    __syncthreads();

    if (tid == 0) {
        unsigned int* done = (unsigned int*)&ws[16];
        unsigned int ticket = atomicAdd(done, 1u);
        islast = (ticket == (unsigned int)(nblocks - 1)) ? 1 : 0;
    }
    __syncthreads();

    // Last block finalizes (device-scope atomic reads -> coherent).
    if (islast && tid < 64) {
        double dv = 0.0;
        unsigned long long totv = 0ULL;
        if (tid < NBINS) {
            long long s = (long long)atomicAdd(&ws[tid], 0ULL);
            dv = fabs((double)s);
        }
        if (tid == NBINS) totv = atomicAdd(&ws[NBINS], 0ULL);
#pragma unroll
        for (int off = 32; off; off >>= 1) dv += __shfl_down(dv, off, 64);
        totv = __shfl(totv, NBINS, 64);
        if (tid == 0) {
            double total = (double)totv;
            if (total < 1.0) total = 1.0;
            out[0] = (float)(dv * (1.0 / 65536.0) / total);
        }
    }
}

extern "C" void kernel_launch(void* const* d_in, const int* in_sizes, int n_in,
                              void* d_out, int out_size, void* d_ws, size_t ws_size,
                              hipStream_t stream)
{
    const float* conf = (const float*)d_in[0];
    const int*   pred = (const int*)d_in[1];
    const int*   targ = (const int*)d_in[2];
    const int*   mask = (const int*)d_in[3];
    long long n    = in_sizes[0];
    int       nvec = (int)(n / 4);

    unsigned long long* ws = (unsigned long long*)d_ws;

    // Zero the 17 u64 accumulator/counter slots (deterministic; capture-safe).
    hipMemsetAsync(d_ws, 0, 17 * sizeof(unsigned long long), stream);

    // 1536 blocks x 256 threads = 6 blocks/CU (best measured: 6 < 7 < 8).
    const int nblocks = 1536;
    ece_fused<<<nblocks, 256, 0, stream>>>(conf, pred, targ, mask, ws,
                                           (float*)d_out, nvec, n, nblocks);
}

// Round 12
// 111.101 us; speedup vs baseline: 3.3243x; 1.0757x over previous
//
#include <hip/hip_runtime.h>

#define NBINS 15

typedef float f32x4 __attribute__((ext_vector_type(4)));
typedef int   i32x4 __attribute__((ext_vector_type(4)));

// Workspace layout (u64 each): [0..14] per-bin signed sum of wv*(c-corr) in
// 2^-16 fixed point (two's-complement wrapped), [15] total mask sum.
// ECE = sum_b |S_b| / 2^16 / total.  (counts/safe are provably redundant:
// empty bins contribute 0 in both formulations.)
//
// Config provenance (measured, dispatch time):
//  - nt loads: 157 -> 109 us (R5).  - 6 blocks/CU best (6:109, 7:114, 8:spill).
//  - 2-stage pipeline: 107.5 us, VGPR 40, no spill (R8 = this kernel).
//  - 3-stage: VGPR allocator bails -> 185MB scratch spill, 374 us (R9).
//  - fused last-block finalize: +6 us net (R11). __threadfence there = +245 us.

// Process one float4/int4 chunk into acc[]/tot (branchless 15-way select).
#define PROC(cv, pv, tv, mv)                                              \
    {                                                                     \
        _Pragma("unroll")                                                 \
        for (int k = 0; k < 4; ++k) {                                     \
            float c = (cv)[k];                                            \
            int   m = (mv)[k];                                            \
            tot += (unsigned int)m;                                       \
            bool valid = (m != 0) & (c > 0.0f) & (c <= 1.0f);             \
            int bin = (int)ceilf(c * 15.0f) - 1;                          \
            bin = min(max(bin, 0), NBINS - 1);                            \
            bin = valid ? bin : -1;                                       \
            float corr = ((pv)[k] == (tv)[k]) ? 1.0f : 0.0f;              \
            int d = (int)rintf((c - corr) * 65536.0f);                    \
            _Pragma("unroll")                                             \
            for (int b = 0; b < NBINS; ++b)                               \
                acc[b] += (bin == b) ? d : 0;                             \
        }                                                                 \
    }

__global__ __launch_bounds__(256, 6) void ece_partial(
    const float* __restrict__ conf,
    const int*   __restrict__ pred,
    const int*   __restrict__ targ,
    const int*   __restrict__ mask,
    unsigned long long* __restrict__ ws,
    int nvec)
{
    __shared__ unsigned int hsum[16];
    __shared__ unsigned long long stot;

    const int tid  = threadIdx.x;
    const int lane = tid & 63;

    if (tid < 16) hsum[tid] = 0u;
    if (tid == 0) stot = 0ULL;
    __syncthreads();

    const int gid    = blockIdx.x * blockDim.x + tid;
    const int stride = gridDim.x * blockDim.x;

    const f32x4* __restrict__ c4p = (const f32x4*)conf;
    const i32x4* __restrict__ p4p = (const i32x4*)pred;
    const i32x4* __restrict__ t4p = (const i32x4*)targ;
    const i32x4* __restrict__ m4p = (const i32x4*)mask;

    int acc[NBINS];
#pragma unroll
    for (int b = 0; b < NBINS; ++b) acc[b] = 0;

    unsigned int tot = 0;

    // Two-stage software pipeline: while computing stage X, the other
    // stage's 4 nt loads are in flight.
    int k = gid;
    if (k + stride < nvec) {
        f32x4 c0 = __builtin_nontemporal_load(c4p + k);
        i32x4 p0 = __builtin_nontemporal_load(p4p + k);
        i32x4 t0 = __builtin_nontemporal_load(t4p + k);
        i32x4 m0 = __builtin_nontemporal_load(m4p + k);
        f32x4 c1 = __builtin_nontemporal_load(c4p + (k + stride));
        i32x4 p1 = __builtin_nontemporal_load(p4p + (k + stride));
        i32x4 t1 = __builtin_nontemporal_load(t4p + (k + stride));
        i32x4 m1 = __builtin_nontemporal_load(m4p + (k + stride));

        for (; k + 3 * stride < nvec; k += 2 * stride) {
            PROC(c0, p0, t0, m0);
            {
                const int n0 = k + 2 * stride;
                c0 = __builtin_nontemporal_load(c4p + n0);
                p0 = __builtin_nontemporal_load(p4p + n0);
                t0 = __builtin_nontemporal_load(t4p + n0);
                m0 = __builtin_nontemporal_load(m4p + n0);
            }
            PROC(c1, p1, t1, m1);
            {
                const int n1 = k + 3 * stride;
                c1 = __builtin_nontemporal_load(c4p + n1);
                p1 = __builtin_nontemporal_load(p4p + n1);
                t1 = __builtin_nontemporal_load(t4p + n1);
                m1 = __builtin_nontemporal_load(m4p + n1);
            }
        }
        // Drain the two live stages (indices k, k+stride).
        PROC(c0, p0, t0, m0);
        PROC(c1, p1, t1, m1);
        k += 2 * stride;
    }
    // Tail: at most one leftover chunk per thread (plus the no-pipeline case).
    for (; k < nvec; k += stride) {
        f32x4 cz = __builtin_nontemporal_load(c4p + k);
        i32x4 pz = __builtin_nontemporal_load(p4p + k);
        i32x4 tz = __builtin_nontemporal_load(t4p + k);
        i32x4 mz = __builtin_nontemporal_load(m4p + k);
        PROC(cz, pz, tz, mz);
    }

    // Once-per-block merge.
#pragma unroll
    for (int b = 0; b < NBINS; ++b) {
        int v = acc[b];
#pragma unroll
        for (int off = 32; off; off >>= 1) v += __shfl_down(v, off, 64);
        acc[b] = v;
    }
    unsigned int v = tot;
#pragma unroll
    for (int off = 32; off; off >>= 1) v += __shfl_down(v, off, 64);

    if (lane == 0) {
#pragma unroll
        for (int b = 0; b < NBINS; ++b)
            if (acc[b] != 0) atomicAdd(&hsum[b], (unsigned int)acc[b]);
        atomicAdd(&stot, (unsigned long long)v);
    }
    __syncthreads();

    if (tid < NBINS) {
        int s = (int)hsum[tid];   // block |sum| <= 2^30, fits i32
        if (s != 0)
            atomicAdd(&ws[tid], (unsigned long long)(long long)s);
    }
    if (tid == 0) {
        unsigned long long s = stot;
        if (s) atomicAdd(&ws[NBINS], s);
    }
}

__global__ void ece_scalar_tail(const float* __restrict__ conf,
                                const int*   __restrict__ pred,
                                const int*   __restrict__ targ,
                                const int*   __restrict__ mask,
                                unsigned long long* __restrict__ ws,
                                long long start, long long n)
{
    long long i = start + threadIdx.x;
    if (i < n) {
        float c = conf[i];
        int   m = mask[i];
        if (m) atomicAdd(&ws[NBINS], 1ULL);
        if ((m != 0) & (c > 0.0f) & (c <= 1.0f)) {
            int bin = (int)ceilf(c * 15.0f) - 1;
            bin = min(max(bin, 0), NBINS - 1);
            float corr = (pred[i] == targ[i]) ? 1.0f : 0.0f;
            int d = (int)rintf((c - corr) * 65536.0f);
            atomicAdd(&ws[bin], (unsigned long long)(long long)d);
        }
    }
}

__global__ void ece_final(const unsigned long long* __restrict__ ws,
                          float* __restrict__ out)
{
    int tid = threadIdx.x; // 64 threads
    double v = 0.0;
    if (tid < NBINS) {
        long long s = (long long)ws[tid];
        v = fabs((double)s);
    }
#pragma unroll
    for (int off = 32; off; off >>= 1) v += __shfl_down(v, off, 64);
    if (tid == 0) {
        double total = (double)ws[NBINS];
        if (total < 1.0) total = 1.0;
        out[0] = (float)(v * (1.0 / 65536.0) / total);
    }
}

extern "C" void kernel_launch(void* const* d_in, const int* in_sizes, int n_in,
                              void* d_out, int out_size, void* d_ws, size_t ws_size,
                              hipStream_t stream)
{
    const float* conf = (const float*)d_in[0];
    const int*   pred = (const int*)d_in[1];
    const int*   targ = (const int*)d_in[2];
    const int*   mask = (const int*)d_in[3];
    long long n    = in_sizes[0];
    int       nvec = (int)(n / 4);

    unsigned long long* ws = (unsigned long long*)d_ws;

    // Zero the 16 u64 accumulators every call (deterministic; capture-safe).
    hipMemsetAsync(d_ws, 0, (NBINS + 1) * sizeof(unsigned long long), stream);

    // 1536 blocks x 256 threads = 6 blocks/CU (measured best: 6 < 7 < 8).
    ece_partial<<<1536, 256, 0, stream>>>(conf, pred, targ, mask, ws, nvec);
    if (n % 4 != 0) {
        ece_scalar_tail<<<1, 64, 0, stream>>>(conf, pred, targ, mask, ws,
                                              (long long)nvec * 4, n);
    }
    ece_final<<<1, 64, 0, stream>>>(ws, (float*)d_out);
}